// Round 7
// baseline (211.735 us; speedup 1.0000x reference)
//
#include <hip/hip_runtime.h>

// SparseToDense: scatter features [N,32] into dense [B=4, C=32, D=64, H=64, W=64].
// flat_idx (int32 on device) indexes B*D*H*W sites; output is NCDHW. DHW = 2^18.
//
// R13: MEASUREMENT ROUND. Pipeline = R9b baseline (init, build, gather),
// byte-identical, PLUS one diagnostic dispatch between build and gather:
// the gather's read phase only (same pair-split chain walk + 4x16B feats
// loads), epilogue replaced by a single 4B scratch write (ws+64MB).
//   Readout 1: dur_us - 201.8 ~= cold read-phase time (+~3us gap), since the
//     diagnostic runs on poison-cold feats and the real gather then runs warm.
//   Readout 2: if read phase >= ~79us it ranks in rocprof top-5 with its own
//     duration + FETCH_SIZE; absence bounds it < 79us.
// Pre-committed: dDur +55..80 -> reads dominate, restructure read side next.
//   dDur +10..30 -> reads cheap, A/B NT-vs-regular stores next.
// Context: R9b (store contiguity), R11 (chase removal), R12 (L3 prefetch) all
// clock-normalized NEUTRAL; R10 counters: VALU 1.5%, occ 92%. No single-
// mechanism theory survives; buying attribution before further edits.

#define DHW_LOG2 18
#define DHW (1 << DHW_LOG2)
#define C_CH 32
#define N_SITES_TOTAL (4 * DHW)   // B=4 -> 1048576 sites
#define SITES_PER_BLOCK 128       // 256 threads, 2 threads/site
#define N_TILES (N_SITES_TOTAL / SITES_PER_BLOCK)   // 8192
#define LDS_PAD 132               // 132%32=4 -> 2-way bank aliasing (free)
#define DIAG_OFF (64u << 20)      // scratch offset for diagnostic (64 MB into ws)

typedef float floatx4 __attribute__((ext_vector_type(4)));

__global__ __launch_bounds__(256) void init_head_kernel(int* __restrict__ head, int n)
{
    int t = blockIdx.x * blockDim.x + threadIdx.x;
    if (t < n) head[t] = -1;
}

__global__ __launch_bounds__(256) void build_chains_kernel(
    const int* __restrict__ flat_idx,
    int* __restrict__ head,
    int* __restrict__ next,
    int n_active)
{
    int i = blockIdx.x * blockDim.x + threadIdx.x;
    if (i >= n_active) return;
    int s = flat_idx[i];
    int prev = atomicExch(&head[s], i);   // device-scope int atomic, 4 MB array
    next[i] = prev;
}

// DIAGNOSTIC: gather's read phase, verbatim, minus LDS/store epilogue.
// Writes one float per thread to ws scratch (8 MB) to keep loads alive.
__global__ __launch_bounds__(256) void diag_read_kernel(
    const float* __restrict__ feats,
    const int* __restrict__ head,
    const int* __restrict__ next,
    float* __restrict__ scratch)
{
    const int t  = threadIdx.x;
    const int sl = t >> 1;
    const int h  = t & 1;
    const int S  = blockIdx.x * SITES_PER_BLOCK + sl;

    floatx4 a0 = (floatx4)0.f, a1 = (floatx4)0.f, a2 = (floatx4)0.f, a3 = (floatx4)0.f;

    int p = head[S];
    while (p != -1) {
        const floatx4* row = (const floatx4*)(feats + ((size_t)p * C_CH + h * 16));
        int pn = next[p];
        floatx4 f0 = row[0];
        floatx4 f1 = row[1];
        floatx4 f2 = row[2];
        floatx4 f3 = row[3];
        a0 += f0; a1 += f1; a2 += f2; a3 += f3;
        p = pn;
    }

    floatx4 s4 = a0 + a1 + a2 + a3;
    scratch[blockIdx.x * blockDim.x + t] = s4.x + s4.y + s4.z + s4.w;
}

__global__ __launch_bounds__(256) void gather_kernel(
    const float* __restrict__ feats,
    const int* __restrict__ head,
    const int* __restrict__ next,
    float* __restrict__ out)
{
    __shared__ __align__(16) float lds[C_CH][LDS_PAD];

    const int t  = threadIdx.x;
    const int sl = t >> 1;        // site within block (lane pairs share a site)
    const int h  = t & 1;         // channel half: channels h*16 .. h*16+15
    const int S0 = blockIdx.x * SITES_PER_BLOCK;
    const int S  = S0 + sl;

    floatx4 a0 = (floatx4)0.f, a1 = (floatx4)0.f, a2 = (floatx4)0.f, a3 = (floatx4)0.f;

    int p = head[S];              // coalesced in S; pair lanes broadcast
    while (p != -1) {
        const floatx4* row = (const floatx4*)(feats + ((size_t)p * C_CH + h * 16));
        int pn = next[p];                 // issue next-hop early
        floatx4 f0 = row[0];
        floatx4 f1 = row[1];
        floatx4 f2 = row[2];
        floatx4 f3 = row[3];
        a0 += f0; a1 += f1; a2 += f2; a3 += f3;
        p = pn;
    }

    // Transpose through LDS: lds[c][site_local]; 2-way bank aliasing = free.
    float acc[16] = {
        a0.x, a0.y, a0.z, a0.w,  a1.x, a1.y, a1.z, a1.w,
        a2.x, a2.y, a2.z, a2.w,  a3.x, a3.y, a3.z, a3.w };
    #pragma unroll
    for (int j = 0; j < 16; ++j)
        lds[h * 16 + j][sl] = acc[j];

    __syncthreads();

    // Stream out: 32 lanes x float4 = 512B contiguous per channel per instr.
    const int b   = S0 >> DHW_LOG2;
    const int sp0 = S0 & (DHW - 1);
    #pragma unroll
    for (int it = 0; it < 4; ++it) {
        int q  = it * 256 + t;
        int c  = q >> 5;          // 0..31
        int i4 = q & 31;          // float4 index within this block's channel run
        floatx4 v = *reinterpret_cast<const floatx4*>(&lds[c][i4 * 4]);
        floatx4* o = reinterpret_cast<floatx4*>(
            out + (((size_t)(b * C_CH + c)) << DHW_LOG2) + sp0 + i4 * 4);
        __builtin_nontemporal_store(v, o);
    }
}

// ---- fallback (R3 behavior) if workspace is too small ----
__global__ __launch_bounds__(256) void zero_kernel(float4* __restrict__ out, int n4)
{
    int t = blockIdx.x * blockDim.x + threadIdx.x;
    if (t < n4) out[t] = make_float4(0.f, 0.f, 0.f, 0.f);
}

__global__ __launch_bounds__(256) void scatter_atomic_kernel(
    const float* __restrict__ feats,
    const int* __restrict__ flat_idx,
    float* __restrict__ out,
    int n_active)
{
    int t = blockIdx.x * blockDim.x + threadIdx.x;
    int i = t >> 5, c = t & 31;
    if (i >= n_active) return;
    int s = flat_idx[i];
    atomicAdd(&out[(((size_t)(s >> DHW_LOG2) * C_CH + c) << DHW_LOG2) + (s & (DHW - 1))],
              feats[(size_t)i * C_CH + c]);
}

extern "C" void kernel_launch(void* const* d_in, const int* in_sizes, int n_in,
                              void* d_out, int out_size, void* d_ws, size_t ws_size,
                              hipStream_t stream) {
    const float* feats = (const float*)d_in[0];
    const int*   idx   = (const int*)d_in[1];
    float*       out   = (float*)d_out;
    int n_active = in_sizes[1];   // 400000

    size_t head_bytes = (size_t)N_SITES_TOTAL * sizeof(int);      // 4 MB
    size_t next_bytes = (size_t)n_active * sizeof(int);           // 1.6 MB

    if (ws_size >= head_bytes + next_bytes) {
        int* head = (int*)d_ws;
        int* next = (int*)((char*)d_ws + head_bytes);

        init_head_kernel<<<(N_SITES_TOTAL + 255) / 256, 256, 0, stream>>>(head, N_SITES_TOTAL);
        build_chains_kernel<<<(n_active + 255) / 256, 256, 0, stream>>>(idx, head, next, n_active);

        // Diagnostic read-phase dispatch (cold feats). Skipped if ws too small.
        if (ws_size >= (size_t)DIAG_OFF + (size_t)2 * N_SITES_TOTAL * sizeof(float)) {
            float* scratch = (float*)((char*)d_ws + DIAG_OFF);
            diag_read_kernel<<<N_TILES, 256, 0, stream>>>(feats, head, next, scratch);
        }

        gather_kernel<<<N_TILES, 256, 0, stream>>>(feats, head, next, out);
    } else {
        // fallback: R3 atomic path
        int n4 = out_size >> 2;
        zero_kernel<<<(n4 + 255) / 256, 256, 0, stream>>>((float4*)out, n4);
        int total = n_active * C_CH;
        scatter_atomic_kernel<<<(total + 255) / 256, 256, 0, stream>>>(feats, idx, out, n_active);
    }
}

// Round 8
// 200.481 us; speedup vs baseline: 1.0561x; 1.0561x over previous
//
#include <hip/hip_runtime.h>

// SparseToDense: scatter features [N,32] into dense [B=4, C=32, D=64, H=64, W=64].
// flat_idx (int32 on device) indexes B*D*H*W sites; output is NCDHW. DHW = 2^18.
//
// R14: drop NONTEMPORAL on the output stores -> plain cached stores.
//   R13 measurement: the ENTIRE cold read phase (chain walk + 51MB random
//   feats reads) is ~10us -- at the BW floor. R10 calibration: timed region =
//   out-poison fill (21us) + my kernels only (512MB ws fill is outside).
//   => gather ~= 153us, of which ~143us is the store epilogue: 134MB at
//   0.94 TB/s, 7x slower than fillBuffer on the same memory. Every "neutral"
//   experiment (R9b contiguity, R11 buckets, R12 prefetch) is explained:
//   the NT store stream was always ~95% of gather.
//   NT stores were adopted to "protect L2 chain data" -- but reads are worth
//   10us total; nothing to protect. NT no-allocate plausibly bypasses L2
//   write-combining: 16B/lane partial bursts to DRAM instead of full dirty
//   lines drained sequentially (fill + m13's 6.3TB/s copy use cached stores).
//   ONE variable changed: __builtin_nontemporal_store -> plain store.
// Kept: R9b LDS-transpose epilogue (512B contiguous per wave instr); cached
//   loads (R6: NT loads regress); 2 threads/site; chain build; 3 dispatches.
// Prediction: gather 153 -> 30-45us, dur 201.5 -> ~80-100us. If neutral, NT
//   is innocent -> next: channel-major grid remap for DRAM stream locality.

#define DHW_LOG2 18
#define DHW (1 << DHW_LOG2)
#define C_CH 32
#define N_SITES_TOTAL (4 * DHW)   // B=4 -> 1048576 sites
#define SITES_PER_BLOCK 128       // 256 threads, 2 threads/site
#define N_TILES (N_SITES_TOTAL / SITES_PER_BLOCK)   // 8192
#define LDS_PAD 132               // 132%32=4 -> 2-way bank aliasing (free)

typedef float floatx4 __attribute__((ext_vector_type(4)));

__global__ __launch_bounds__(256) void init_head_kernel(int* __restrict__ head, int n)
{
    int t = blockIdx.x * blockDim.x + threadIdx.x;
    if (t < n) head[t] = -1;
}

__global__ __launch_bounds__(256) void build_chains_kernel(
    const int* __restrict__ flat_idx,
    int* __restrict__ head,
    int* __restrict__ next,
    int n_active)
{
    int i = blockIdx.x * blockDim.x + threadIdx.x;
    if (i >= n_active) return;
    int s = flat_idx[i];
    int prev = atomicExch(&head[s], i);   // device-scope int atomic, 4 MB array
    next[i] = prev;
}

__global__ __launch_bounds__(256) void gather_kernel(
    const float* __restrict__ feats,
    const int* __restrict__ head,
    const int* __restrict__ next,
    float* __restrict__ out)
{
    __shared__ __align__(16) float lds[C_CH][LDS_PAD];

    const int t  = threadIdx.x;
    const int sl = t >> 1;        // site within block (lane pairs share a site)
    const int h  = t & 1;         // channel half: channels h*16 .. h*16+15
    const int S0 = blockIdx.x * SITES_PER_BLOCK;
    const int S  = S0 + sl;

    floatx4 a0 = (floatx4)0.f, a1 = (floatx4)0.f, a2 = (floatx4)0.f, a3 = (floatx4)0.f;

    int p = head[S];              // coalesced in S; pair lanes broadcast
    while (p != -1) {
        const floatx4* row = (const floatx4*)(feats + ((size_t)p * C_CH + h * 16));
        int pn = next[p];                 // issue next-hop early
        floatx4 f0 = row[0];              // read phase measured ~10us total (R13)
        floatx4 f1 = row[1];
        floatx4 f2 = row[2];
        floatx4 f3 = row[3];
        a0 += f0; a1 += f1; a2 += f2; a3 += f3;
        p = pn;
    }

    // Transpose through LDS: lds[c][site_local]; 2-way bank aliasing = free.
    float acc[16] = {
        a0.x, a0.y, a0.z, a0.w,  a1.x, a1.y, a1.z, a1.w,
        a2.x, a2.y, a2.z, a2.w,  a3.x, a3.y, a3.z, a3.w };
    #pragma unroll
    for (int j = 0; j < 16; ++j)
        lds[h * 16 + j][sl] = acc[j];

    __syncthreads();

    // Stream out: 32 lanes x float4 = 512B contiguous per channel per instr.
    // PLAIN cached stores (the single variable changed this round): let L2
    // write-combine full lines and drain sequentially like fillBuffer does.
    const int b   = S0 >> DHW_LOG2;
    const int sp0 = S0 & (DHW - 1);
    #pragma unroll
    for (int it = 0; it < 4; ++it) {
        int q  = it * 256 + t;
        int c  = q >> 5;          // 0..31
        int i4 = q & 31;          // float4 index within this block's channel run
        floatx4 v = *reinterpret_cast<const floatx4*>(&lds[c][i4 * 4]);
        floatx4* o = reinterpret_cast<floatx4*>(
            out + (((size_t)(b * C_CH + c)) << DHW_LOG2) + sp0 + i4 * 4);
        *o = v;
    }
}

// ---- fallback (R3 behavior) if workspace is too small ----
__global__ __launch_bounds__(256) void zero_kernel(float4* __restrict__ out, int n4)
{
    int t = blockIdx.x * blockDim.x + threadIdx.x;
    if (t < n4) out[t] = make_float4(0.f, 0.f, 0.f, 0.f);
}

__global__ __launch_bounds__(256) void scatter_atomic_kernel(
    const float* __restrict__ feats,
    const int* __restrict__ flat_idx,
    float* __restrict__ out,
    int n_active)
{
    int t = blockIdx.x * blockDim.x + threadIdx.x;
    int i = t >> 5, c = t & 31;
    if (i >= n_active) return;
    int s = flat_idx[i];
    atomicAdd(&out[(((size_t)(s >> DHW_LOG2) * C_CH + c) << DHW_LOG2) + (s & (DHW - 1))],
              feats[(size_t)i * C_CH + c]);
}

extern "C" void kernel_launch(void* const* d_in, const int* in_sizes, int n_in,
                              void* d_out, int out_size, void* d_ws, size_t ws_size,
                              hipStream_t stream) {
    const float* feats = (const float*)d_in[0];
    const int*   idx   = (const int*)d_in[1];
    float*       out   = (float*)d_out;
    int n_active = in_sizes[1];   // 400000

    size_t head_bytes = (size_t)N_SITES_TOTAL * sizeof(int);      // 4 MB
    size_t next_bytes = (size_t)n_active * sizeof(int);           // 1.6 MB

    if (ws_size >= head_bytes + next_bytes) {
        int* head = (int*)d_ws;
        int* next = (int*)((char*)d_ws + head_bytes);

        init_head_kernel<<<(N_SITES_TOTAL + 255) / 256, 256, 0, stream>>>(head, N_SITES_TOTAL);
        build_chains_kernel<<<(n_active + 255) / 256, 256, 0, stream>>>(idx, head, next, n_active);
        // 8192 blocks x 256 threads; each block owns 128 consecutive sites.
        gather_kernel<<<N_TILES, 256, 0, stream>>>(feats, head, next, out);
    } else {
        // fallback: R3 atomic path
        int n4 = out_size >> 2;
        zero_kernel<<<(n4 + 255) / 256, 256, 0, stream>>>((float4*)out, n4);
        int total = n_active * C_CH;
        scatter_atomic_kernel<<<(total + 255) / 256, 256, 0, stream>>>(feats, idx, out, n_active);
    }
}